// Round 1
// baseline (426.332 us; speedup 1.0000x reference)
//
#include <hip/hip_runtime.h>

#define NUM_CATEGORIES 1024
#define TOKEN_DIM      1024
#define BATCH          65536

// One wave (64 lanes) per batch row:
//  1) scan x[row, :] in float4 chunks (256 floats / iter), ballot-early-exit
//     when the one-hot 1.0 is found;
//  2) copy ortho_basis[idx, :] (4 KB) to out[row, :] with float4 stores.
__global__ __launch_bounds__(256) void ortho_embed_gather(
    const float* __restrict__ x,          // [BATCH, NUM_CATEGORIES]
    const float* __restrict__ basis,      // [NUM_CATEGORIES, TOKEN_DIM]
    float* __restrict__ out)              // [BATCH, TOKEN_DIM]
{
    const int lane        = threadIdx.x & 63;
    const int wave_in_blk = threadIdx.x >> 6;
    const int waves_per_blk = blockDim.x >> 6;
    const int gwave     = blockIdx.x * waves_per_blk + wave_in_blk;
    const int num_waves = gridDim.x * waves_per_blk;

    for (int row = gwave; row < BATCH; row += num_waves) {
        const float4* __restrict__ xr =
            reinterpret_cast<const float4*>(x + (size_t)row * NUM_CATEGORIES);

        int idx = 0;
        #pragma unroll
        for (int it = 0; it < NUM_CATEGORIES / 256; ++it) {
            float4 v = xr[it * 64 + lane];
            // local sub-position of a nonzero, 0..3; -1 if none
            int sub = -1;
            if (v.w != 0.0f) sub = 3;
            if (v.z != 0.0f) sub = 2;
            if (v.y != 0.0f) sub = 1;
            if (v.x != 0.0f) sub = 0;
            unsigned long long m = __ballot(sub >= 0);
            if (m) {
                int src_lane  = __ffsll((long long)m) - 1;
                int candidate = (it * 64 + lane) * 4 + (sub < 0 ? 0 : sub);
                idx = __shfl(candidate, src_lane);
                break;   // wave-uniform (ballot result is uniform)
            }
        }

        const float4* __restrict__ br =
            reinterpret_cast<const float4*>(basis + (size_t)idx * TOKEN_DIM);
        float4* __restrict__ orow =
            reinterpret_cast<float4*>(out + (size_t)row * TOKEN_DIM);
        #pragma unroll
        for (int it = 0; it < TOKEN_DIM / 256; ++it) {
            orow[it * 64 + lane] = br[it * 64 + lane];
        }
    }
}

extern "C" void kernel_launch(void* const* d_in, const int* in_sizes, int n_in,
                              void* d_out, int out_size, void* d_ws, size_t ws_size,
                              hipStream_t stream) {
    const float* x     = (const float*)d_in[0];   // [BATCH, NUM_CATEGORIES] f32 one-hot
    const float* basis = (const float*)d_in[1];   // [NUM_CATEGORIES, TOKEN_DIM] f32
    float* out = (float*)d_out;                   // [BATCH, TOKEN_DIM] f32

    // 2048 blocks x 256 threads = 8192 waves (full residency: 256 CU x 32 waves),
    // each wave grid-strides over 8 rows.
    dim3 grid(2048), block(256);
    hipLaunchKernelGGL(ortho_embed_gather, grid, block, 0, stream, x, basis, out);
}